// Round 4
// baseline (1104.351 us; speedup 1.0000x reference)
//
#include <hip/hip_runtime.h>

#define T_LEN 2048
#define DH 256
#define NCHUNK (T_LEN / 16)

typedef short short8 __attribute__((ext_vector_type(8)));
typedef float f32x4 __attribute__((ext_vector_type(4)));

__device__ __forceinline__ unsigned short f2bf(float f) {
  unsigned u = __builtin_bit_cast(unsigned, f);
  u += 0x7fffu + ((u >> 16) & 1u);   // round-to-nearest-even
  return (unsigned short)(u >> 16);
}

// Raw WG barrier: flush this wave's LDS ops, barrier, fence the scheduler.
// Deliberately does NOT drain vmcnt — prefetch loads / h stores stay in
// flight across steps (no cross-wave hazard goes through global memory).
#define WG_BARRIER() do {                                   \
  __builtin_amdgcn_sched_barrier(0);                        \
  asm volatile("s_waitcnt lgkmcnt(0)" ::: "memory");        \
  __builtin_amdgcn_s_barrier();                             \
  __builtin_amdgcn_sched_barrier(0);                        \
} while (0)

// ---------------------------------------------------------------------------
// Phase 1: out = x @ W_in + b_in + b_h, stored in a PERMUTED column layout:
//   value of column c = 64a+16b+r   (a=c>>6, b=(c>>4)&3, r=c&15)
//   is stored at position p(c) = 64a + 4r + b.
// d_out is scratch until phase 2 overwrites each row with h_t (in canonical
// layout), so the intermediate layout is free. This makes phase-2's per-step
// x_proj read a single ds_read_b128 per wave, and phase-1's stores packed
// dwordx4 (lane r stores its 4 b-values contiguously).
// MFMA 16x16x32 bf16. A[m][k]: m=lane&15, k=(lane>>4)*8+j; B same k, c=lane&15;
// D: c=lane&15, m=(lane>>4)*4+r.
// ---------------------------------------------------------------------------
__global__ __launch_bounds__(256, 1) void xproj_gemm(
    const float* __restrict__ x, const float* __restrict__ W_in,
    const float* __restrict__ b_in, const float* __restrict__ b_h,
    float* __restrict__ out) {
  const int tid  = threadIdx.x;
  const int lane = tid & 63;
  const int w    = tid >> 6;
  const int l15  = lane & 15;
  const int lg   = lane >> 4;
  const int koff = lg * 8;
  const int m0   = blockIdx.x * 128;

  short8 Bf[4][8];
#pragma unroll
  for (int n = 0; n < 4; ++n) {
    const int c = 64 * w + 16 * n + l15;
#pragma unroll
    for (int kk = 0; kk < 8; ++kk) {
      short8 bf;
#pragma unroll
      for (int j = 0; j < 8; ++j)
        bf[j] = (short)f2bf(W_in[(32 * kk + koff + j) * DH + c]);
      Bf[n][kk] = bf;
    }
  }
  float bin[4];
#pragma unroll
  for (int n = 0; n < 4; ++n) {
    const int c = 64 * w + 16 * n + l15;
    bin[n] = b_in[c] + b_h[c];
  }

  for (int slab = 0; slab < 8; ++slab) {
    const float* xr = x + (size_t)(m0 + slab * 16 + l15) * DH;
    short8 A[8];
#pragma unroll
    for (int kk = 0; kk < 8; ++kk) {
      f32x4 v0 = *(const f32x4*)(xr + 32 * kk + koff);
      f32x4 v1 = *(const f32x4*)(xr + 32 * kk + koff + 4);
      short8 a;
      a[0] = f2bf(v0[0]); a[1] = f2bf(v0[1]); a[2] = f2bf(v0[2]); a[3] = f2bf(v0[3]);
      a[4] = f2bf(v1[0]); a[5] = f2bf(v1[1]); a[6] = f2bf(v1[2]); a[7] = f2bf(v1[3]);
      A[kk] = a;
    }
    f32x4 acc[4];
#pragma unroll
    for (int n = 0; n < 4; ++n) acc[n] = (f32x4){0.f, 0.f, 0.f, 0.f};
#pragma unroll
    for (int kk = 0; kk < 8; ++kk)
#pragma unroll
      for (int n = 0; n < 4; ++n)
        acc[n] = __builtin_amdgcn_mfma_f32_16x16x32_bf16(A[kk], Bf[n][kk], acc[n], 0, 0, 0);
    // Packed permuted store: row m0+slab*16+lg*4+r, positions 64w+4*l15+{0..3}.
#pragma unroll
    for (int r = 0; r < 4; ++r) {
      f32x4 o;
#pragma unroll
      for (int n = 0; n < 4; ++n) o[n] = acc[n][r] + bin[n];
      *(f32x4*)(out + (size_t)(m0 + slab * 16 + lg * 4 + r) * DH + 64 * w + 4 * l15) = o;
    }
  }
}

// ---------------------------------------------------------------------------
// Phase 2: serial scan. Grid 32 (one WG per batch) x 256 thr (4 waves).
// Wave w owns cols [64w, 64w+64) -> Bf[4][8] = 128 VGPRs/lane.
// Per-step LDS budget (the critical resource): 4 waves x (8 A-frag
// ds_read_b128 + 1 xb ds_read_b128 + 4 ds_write_b16) = 52 instructions
// (R2 had 112 across 8 waves -> LDS pipe was the hidden ~500 cyc/step).
// xb consumed in the EPILOGUE (off the MFMA critical path; R3's acc-seed put
// it in front and regressed). h stores go straight to global (no wait needed).
// ---------------------------------------------------------------------------
__global__ __launch_bounds__(256, 1) void rnn_scan(
    const float* __restrict__ h0, const float* __restrict__ W_h,
    float* __restrict__ out) {
  __shared__ __align__(16) unsigned short hbuf[2][DH];
  __shared__ __align__(16) float xpb[2][16 * DH];

  const int tid  = threadIdx.x;
  const int lane = tid & 63;
  const int w    = tid >> 6;         // 0..3
  const int l15  = lane & 15;
  const int lg   = lane >> 4;
  const int koff = lg * 8;
  const int b    = blockIdx.x;
  float* outb = out + (size_t)b * T_LEN * DH;

  // Issue chunk-0 x_proj loads first so they fly under the W_h fragment load.
  f32x4 st[4];
#pragma unroll
  for (int i = 0; i < 4; ++i)
    st[i] = *(const f32x4*)(outb + i * 1024 + tid * 4);

  // W_h bf16 fragments: wave w owns cols [64w, 64w+64) as 4 16-col tiles.
  short8 Bf[4][8];
#pragma unroll
  for (int n = 0; n < 4; ++n) {
    const int c = 64 * w + 16 * n + l15;
#pragma unroll
    for (int kk = 0; kk < 8; ++kk) {
      short8 bf;
#pragma unroll
      for (int j = 0; j < 8; ++j)
        bf[j] = (short)f2bf(W_h[(32 * kk + koff + j) * DH + c]);
      Bf[n][kk] = bf;
    }
  }

  hbuf[0][tid] = f2bf(h0[b * DH + tid]);
#pragma unroll
  for (int i = 0; i < 4; ++i)
    *(f32x4*)(&xpb[0][i * 1024 + tid * 4]) = st[i];
#pragma unroll
  for (int i = 0; i < 4; ++i)
    st[i] = *(const f32x4*)(outb + 4096 + i * 1024 + tid * 4);
  __syncthreads();

  // A fragments: rows 1..15 are zeros, set ONCE; only l15==0 lanes overwrite.
  short8 A[8];
#pragma unroll
  for (int kk = 0; kk < 8; ++kk) A[kk] = (short8){0, 0, 0, 0, 0, 0, 0, 0};

  for (int t = 0; t < T_LEN; ++t) {
    const unsigned short* hb = &hbuf[t & 1][0];
    if (l15 == 0) {
#pragma unroll
      for (int kk = 0; kk < 8; ++kk)
        A[kk] = *(const short8*)(hb + 32 * kk + koff);
    }
    // Per-step x_proj(+biases): ONE b128 read per lane<16 (permuted layout).
    f32x4 xb4;
    if (lane < 16)
      xb4 = *(const f32x4*)(&xpb[(t >> 4) & 1][(t & 15) * DH + 64 * w + 4 * lane]);

    // 32 MFMAs: 4 col-tiles x 2 sub-accumulators of depth 4 (8 indep chains).
    f32x4 ac[4][2];
#pragma unroll
    for (int n = 0; n < 4; ++n) {
      ac[n][0] = (f32x4){0.f, 0.f, 0.f, 0.f};
      ac[n][1] = (f32x4){0.f, 0.f, 0.f, 0.f};
    }
#pragma unroll
    for (int d = 0; d < 4; ++d)
#pragma unroll
      for (int n = 0; n < 4; ++n)
        ac[n][0] = __builtin_amdgcn_mfma_f32_16x16x32_bf16(A[d], Bf[n][d], ac[n][0], 0, 0, 0);
#pragma unroll
    for (int d = 4; d < 8; ++d)
#pragma unroll
      for (int n = 0; n < 4; ++n)
        ac[n][1] = __builtin_amdgcn_mfma_f32_16x16x32_bf16(A[d], Bf[n][d], ac[n][1], 0, 0, 0);

    // Valid output row is m=0 -> lanes 0..15, element 0.
    if (lane < 16) {
#pragma unroll
      for (int n = 0; n < 4; ++n) {
        const int c = 64 * w + 16 * n + lane;
        float v = (ac[n][0][0] + ac[n][1][0]) + xb4[n];
        v = fmaxf(v, 0.0f);
        hbuf[(t + 1) & 1][c] = f2bf(v);        // first: next step waits on this
        outb[(size_t)t * DH + c] = v;          // direct store, no wait needed
      }
    }

    if ((t & 15) == 15) {
      WG_BARRIER();  // all reads of xp chunk + h writes complete
      const int nc = (t >> 4) + 1;  // chunk to publish (regs -> LDS)
      if (nc < NCHUNK) {
#pragma unroll
        for (int i = 0; i < 4; ++i)
          *(f32x4*)(&xpb[nc & 1][i * 1024 + tid * 4]) = st[i];
        const int pc = nc + 1;      // prefetch following chunk
        if (pc < NCHUNK) {
#pragma unroll
          for (int i = 0; i < 4; ++i)
            st[i] = *(const f32x4*)(outb + (size_t)pc * 4096 + i * 1024 + tid * 4);
        }
      }
      WG_BARRIER();  // xpb chunk visible before next step reads it
    } else {
      WG_BARRIER();  // h_{t+1} visible before next step's A-frag reads
    }
  }
}

extern "C" void kernel_launch(void* const* d_in, const int* in_sizes, int n_in,
                              void* d_out, int out_size, void* d_ws, size_t ws_size,
                              hipStream_t stream) {
  const float* x    = (const float*)d_in[0];
  const float* h0   = (const float*)d_in[1];
  const float* W_in = (const float*)d_in[2];
  const float* b_in = (const float*)d_in[3];
  const float* W_h  = (const float*)d_in[4];
  const float* b_h  = (const float*)d_in[5];
  float* out = (float*)d_out;

  hipLaunchKernelGGL(xproj_gemm, dim3(512), dim3(256), 0, stream, x, W_in, b_in, b_h, out);
  hipLaunchKernelGGL(rnn_scan, dim3(32), dim3(256), 0, stream, h0, W_h, out);
}

// Round 5
// 942.526 us; speedup vs baseline: 1.1717x; 1.1717x over previous
//
#include <hip/hip_runtime.h>

#define T_LEN 2048
#define DH 256
#define NCHUNK (T_LEN / 16)

typedef short short8 __attribute__((ext_vector_type(8)));
typedef float f32x4 __attribute__((ext_vector_type(4)));

__device__ __forceinline__ unsigned short f2bf(float f) {
  unsigned u = __builtin_bit_cast(unsigned, f);
  u += 0x7fffu + ((u >> 16) & 1u);   // round-to-nearest-even
  return (unsigned short)(u >> 16);
}

// Raw WG barrier: flush this wave's LDS ops, barrier, fence the scheduler.
// Deliberately does NOT drain vmcnt — prefetch loads / chunk stores stay in
// flight across steps (no cross-wave hazard goes through global memory).
#define WG_BARRIER() do {                                   \
  __builtin_amdgcn_sched_barrier(0);                        \
  asm volatile("s_waitcnt lgkmcnt(0)" ::: "memory");        \
  __builtin_amdgcn_s_barrier();                             \
  __builtin_amdgcn_sched_barrier(0);                        \
} while (0)

// ---------------------------------------------------------------------------
// Phase 1: out = x @ W_in + b_in + b_h   (b_h folded in so the scan epilogue
// is shorter). Grid 512 x 256 thr; wave w owns cols [64w, 64w+64).
// MFMA 16x16x32 bf16. A[m][k]: m=lane&15, k=(lane>>4)*8+j; B same k, c=lane&15;
// D: c=lane&15, m=(lane>>4)*4+r.
// ---------------------------------------------------------------------------
__global__ __launch_bounds__(256, 1) void xproj_gemm(
    const float* __restrict__ x, const float* __restrict__ W_in,
    const float* __restrict__ b_in, const float* __restrict__ b_h,
    float* __restrict__ out) {
  const int tid  = threadIdx.x;
  const int lane = tid & 63;
  const int w    = tid >> 6;
  const int l15  = lane & 15;
  const int lg   = lane >> 4;
  const int koff = lg * 8;
  const int m0   = blockIdx.x * 128;

  short8 Bf[4][8];
#pragma unroll
  for (int n = 0; n < 4; ++n) {
    const int c = 64 * w + 16 * n + l15;
#pragma unroll
    for (int kk = 0; kk < 8; ++kk) {
      short8 bf;
#pragma unroll
      for (int j = 0; j < 8; ++j)
        bf[j] = (short)f2bf(W_in[(32 * kk + koff + j) * DH + c]);
      Bf[n][kk] = bf;
    }
  }
  float bin[4];
#pragma unroll
  for (int n = 0; n < 4; ++n) {
    const int c = 64 * w + 16 * n + l15;
    bin[n] = b_in[c] + b_h[c];
  }

  for (int slab = 0; slab < 8; ++slab) {
    const float* xr = x + (size_t)(m0 + slab * 16 + l15) * DH;
    short8 A[8];
#pragma unroll
    for (int kk = 0; kk < 8; ++kk) {
      f32x4 v0 = *(const f32x4*)(xr + 32 * kk + koff);
      f32x4 v1 = *(const f32x4*)(xr + 32 * kk + koff + 4);
      short8 a;
      a[0] = f2bf(v0[0]); a[1] = f2bf(v0[1]); a[2] = f2bf(v0[2]); a[3] = f2bf(v0[3]);
      a[4] = f2bf(v1[0]); a[5] = f2bf(v1[1]); a[6] = f2bf(v1[2]); a[7] = f2bf(v1[3]);
      A[kk] = a;
    }
    f32x4 acc[4];
#pragma unroll
    for (int n = 0; n < 4; ++n) acc[n] = (f32x4){0.f, 0.f, 0.f, 0.f};
#pragma unroll
    for (int kk = 0; kk < 8; ++kk)
#pragma unroll
      for (int n = 0; n < 4; ++n)
        acc[n] = __builtin_amdgcn_mfma_f32_16x16x32_bf16(A[kk], Bf[n][kk], acc[n], 0, 0, 0);
#pragma unroll
    for (int n = 0; n < 4; ++n) {
      const int c = 64 * w + 16 * n + l15;
#pragma unroll
      for (int r = 0; r < 4; ++r)
        out[(size_t)(m0 + slab * 16 + lg * 4 + r) * DH + c] = acc[n][r] + bin[n];
    }
  }
}

// ---------------------------------------------------------------------------
// Phase 2: serial scan. Grid 32 (one WG per batch) x 512 thr (8 waves).
// EXACTLY the R2 structure (892 us) except the MFMA dataflow:
//   R2: 2 sub-accumulators of depth 4  -> 8 dependent levels (~512 cyc if
//       MFMA latency ~64).
//   R5: ac[2][4] = 8 independent chains of depth 2, ordered d-outer/q-mid/
//       n-inner so chain-mates are 8 instructions (~40 cyc) apart.
// Everything else (xout staging, chunk-boundary coalesced stores, xb read in
// epilogue, barrier discipline) is unchanged — single-variable A/B vs R2.
// ---------------------------------------------------------------------------
__global__ __launch_bounds__(512, 2) void rnn_scan(
    const float* __restrict__ h0, const float* __restrict__ W_h,
    float* __restrict__ out) {
  __shared__ __align__(16) unsigned short hbuf[2][DH];
  __shared__ __align__(16) float xpb[2][16 * DH];
  __shared__ __align__(16) float xout[16 * DH];

  const int tid  = threadIdx.x;
  const int lane = tid & 63;
  const int w    = tid >> 6;         // 0..7
  const int l15  = lane & 15;
  const int lg   = lane >> 4;
  const int koff = lg * 8;
  const int b    = blockIdx.x;
  float* outb = out + (size_t)b * T_LEN * DH;

  // Issue chunk-0 x_proj loads first so they fly under the W_h fragment load.
  f32x4 st[2];
#pragma unroll
  for (int i = 0; i < 2; ++i)
    st[i] = *(const f32x4*)(outb + i * 2048 + tid * 4);

  // W_h bf16 fragments: wave w owns cols [32w, 32w+32) as 2 16-col tiles.
  short8 Bf[2][8];
#pragma unroll
  for (int n = 0; n < 2; ++n) {
    const int c = 32 * w + 16 * n + l15;
#pragma unroll
    for (int kk = 0; kk < 8; ++kk) {
      short8 bf;
#pragma unroll
      for (int j = 0; j < 8; ++j)
        bf[j] = (short)f2bf(W_h[(32 * kk + koff + j) * DH + c]);
      Bf[n][kk] = bf;
    }
  }

  if (tid < DH) hbuf[0][tid] = f2bf(h0[b * DH + tid]);
#pragma unroll
  for (int i = 0; i < 2; ++i)
    *(f32x4*)(&xpb[0][i * 2048 + tid * 4]) = st[i];
#pragma unroll
  for (int i = 0; i < 2; ++i)
    st[i] = *(const f32x4*)(outb + 4096 + i * 2048 + tid * 4);
  __syncthreads();

  // A fragments: rows 1..15 are zeros, set ONCE; only l15==0 lanes overwrite.
  short8 A[8];
#pragma unroll
  for (int kk = 0; kk < 8; ++kk) A[kk] = (short8){0, 0, 0, 0, 0, 0, 0, 0};

  for (int t = 0; t < T_LEN; ++t) {
    const unsigned short* hb = &hbuf[t & 1][0];
    if (l15 == 0) {
#pragma unroll
      for (int kk = 0; kk < 8; ++kk)
        A[kk] = *(const short8*)(hb + 32 * kk + koff);
    }
    // x_proj(+biases) for this step, read early (off the MFMA wait path).
    float xb[2];
    if (lane < 16) {
#pragma unroll
      for (int n = 0; n < 2; ++n)
        xb[n] = xpb[(t >> 4) & 1][(t & 15) * DH + 32 * w + 16 * n + lane];
    }

    // 16 MFMAs: 8 independent chains (2 col-tiles x 4) of depth 2.
    // Chain (n,q) takes K-tiles kk=q (level d=0) and kk=q+4 (level d=1);
    // its two MFMAs are 8 instructions apart in issue order.
    f32x4 ac[2][4];
#pragma unroll
    for (int n = 0; n < 2; ++n)
#pragma unroll
      for (int q = 0; q < 4; ++q) ac[n][q] = (f32x4){0.f, 0.f, 0.f, 0.f};
#pragma unroll
    for (int d = 0; d < 2; ++d)
#pragma unroll
      for (int q = 0; q < 4; ++q)
#pragma unroll
        for (int n = 0; n < 2; ++n)
          ac[n][q] = __builtin_amdgcn_mfma_f32_16x16x32_bf16(
              A[q + 4 * d], Bf[n][q + 4 * d], ac[n][q], 0, 0, 0);

    // Valid output row is m=0 -> lanes 0..15, element 0.
    if (lane < 16) {
#pragma unroll
      for (int n = 0; n < 2; ++n) {
        const int c = 32 * w + 16 * n + lane;
        float v = ((ac[n][0][0] + ac[n][1][0]) + (ac[n][2][0] + ac[n][3][0])) + xb[n];
        v = fmaxf(v, 0.0f);
        xout[(t & 15) * DH + c] = v;           // staged for the chunk dump
        hbuf[(t + 1) & 1][c] = f2bf(v);
      }
    }

    if ((t & 15) == 15) {
      WG_BARRIER();  // all reads of xp chunk + h/xout writes complete
      const int cc = t >> 4;      // finished chunk
      const int nc = cc + 1;
      if (nc < NCHUNK) {
        // publish prefetched chunk (waits vmcnt(2): 2 stores newer than loads)
#pragma unroll
        for (int i = 0; i < 2; ++i)
          *(f32x4*)(&xpb[nc & 1][i * 2048 + tid * 4]) = st[i];
        const int pc = nc + 1;
        if (pc < NCHUNK) {
#pragma unroll
          for (int i = 0; i < 2; ++i)
            st[i] = *(const f32x4*)(outb + (size_t)pc * 4096 + i * 2048 + tid * 4);
        }
      }
      // dump finished h chunk: LDS -> regs -> coalesced global stores
      f32x4 o[2];
#pragma unroll
      for (int i = 0; i < 2; ++i)
        o[i] = *(const f32x4*)(&xout[i * 2048 + tid * 4]);
#pragma unroll
      for (int i = 0; i < 2; ++i)
        *(f32x4*)(outb + (size_t)cc * 4096 + i * 2048 + tid * 4) = o[i];
      WG_BARRIER();  // xpb chunk + xout reuse visible before next step
    } else {
      WG_BARRIER();  // h_{t+1} visible before next step's A-frag reads
    }
  }
}

extern "C" void kernel_launch(void* const* d_in, const int* in_sizes, int n_in,
                              void* d_out, int out_size, void* d_ws, size_t ws_size,
                              hipStream_t stream) {
  const float* x    = (const float*)d_in[0];
  const float* h0   = (const float*)d_in[1];
  const float* W_in = (const float*)d_in[2];
  const float* b_in = (const float*)d_in[3];
  const float* W_h  = (const float*)d_in[4];
  const float* b_h  = (const float*)d_in[5];
  float* out = (float*)d_out;

  hipLaunchKernelGGL(xproj_gemm, dim3(512), dim3(256), 0, stream, x, W_in, b_in, b_h, out);
  hipLaunchKernelGGL(rnn_scan, dim3(32), dim3(512), 0, stream, h0, W_h, out);
}

// Round 6
// 884.578 us; speedup vs baseline: 1.2484x; 1.0655x over previous
//
#include <hip/hip_runtime.h>

#define T_LEN 2048
#define DH 256
#define NCHUNK (T_LEN / 16)

typedef short short8 __attribute__((ext_vector_type(8)));
typedef float f32x4 __attribute__((ext_vector_type(4)));

__device__ __forceinline__ unsigned short f2bf(float f) {
  unsigned u = __builtin_bit_cast(unsigned, f);
  u += 0x7fffu + ((u >> 16) & 1u);   // round-to-nearest-even
  return (unsigned short)(u >> 16);
}

// Raw WG barrier: flush this wave's LDS ops, barrier, fence the scheduler.
// Deliberately does NOT drain vmcnt — prefetch loads / chunk stores stay in
// flight across steps (no cross-wave hazard goes through global memory).
#define WG_BARRIER() do {                                   \
  __builtin_amdgcn_sched_barrier(0);                        \
  asm volatile("s_waitcnt lgkmcnt(0)" ::: "memory");        \
  __builtin_amdgcn_s_barrier();                             \
  __builtin_amdgcn_sched_barrier(0);                        \
} while (0)

// ---------------------------------------------------------------------------
// Phase 1: out = x @ W_in + b_in + b_h   (b_h folded in so the scan epilogue
// is shorter). Grid 512 x 256 thr; wave w owns cols [64w, 64w+64).
// MFMA 16x16x32 bf16. A[m][k]: m=lane&15, k=(lane>>4)*8+j; B same k, c=lane&15;
// D: c=lane&15, m=(lane>>4)*4+r.
// ---------------------------------------------------------------------------
__global__ __launch_bounds__(256, 1) void xproj_gemm(
    const float* __restrict__ x, const float* __restrict__ W_in,
    const float* __restrict__ b_in, const float* __restrict__ b_h,
    float* __restrict__ out) {
  const int tid  = threadIdx.x;
  const int lane = tid & 63;
  const int w    = tid >> 6;
  const int l15  = lane & 15;
  const int lg   = lane >> 4;
  const int koff = lg * 8;
  const int m0   = blockIdx.x * 128;

  short8 Bf[4][8];
#pragma unroll
  for (int n = 0; n < 4; ++n) {
    const int c = 64 * w + 16 * n + l15;
#pragma unroll
    for (int kk = 0; kk < 8; ++kk) {
      short8 bf;
#pragma unroll
      for (int j = 0; j < 8; ++j)
        bf[j] = (short)f2bf(W_in[(32 * kk + koff + j) * DH + c]);
      Bf[n][kk] = bf;
    }
  }
  float bin[4];
#pragma unroll
  for (int n = 0; n < 4; ++n) {
    const int c = 64 * w + 16 * n + l15;
    bin[n] = b_in[c] + b_h[c];
  }

  for (int slab = 0; slab < 8; ++slab) {
    const float* xr = x + (size_t)(m0 + slab * 16 + l15) * DH;
    short8 A[8];
#pragma unroll
    for (int kk = 0; kk < 8; ++kk) {
      f32x4 v0 = *(const f32x4*)(xr + 32 * kk + koff);
      f32x4 v1 = *(const f32x4*)(xr + 32 * kk + koff + 4);
      short8 a;
      a[0] = f2bf(v0[0]); a[1] = f2bf(v0[1]); a[2] = f2bf(v0[2]); a[3] = f2bf(v0[3]);
      a[4] = f2bf(v1[0]); a[5] = f2bf(v1[1]); a[6] = f2bf(v1[2]); a[7] = f2bf(v1[3]);
      A[kk] = a;
    }
    f32x4 acc[4];
#pragma unroll
    for (int n = 0; n < 4; ++n) acc[n] = (f32x4){0.f, 0.f, 0.f, 0.f};
#pragma unroll
    for (int kk = 0; kk < 8; ++kk)
#pragma unroll
      for (int n = 0; n < 4; ++n)
        acc[n] = __builtin_amdgcn_mfma_f32_16x16x32_bf16(A[kk], Bf[n][kk], acc[n], 0, 0, 0);
#pragma unroll
    for (int n = 0; n < 4; ++n) {
      const int c = 64 * w + 16 * n + l15;
#pragma unroll
      for (int r = 0; r < 4; ++r)
        out[(size_t)(m0 + slab * 16 + lg * 4 + r) * DH + c] = acc[n][r] + bin[n];
    }
  }
}

// ---------------------------------------------------------------------------
// Phase 2: serial scan. Grid 32 (one WG per batch) x 512 thr (8 waves).
// R2's 892us structure with three latency trims:
//   (1) t-loop unrolled by 2: explicit even/odd h-buffers (no (t&1) math),
//       halved loop control, scheduler sees two bodies.
//   (2) epilogue writes hbuf (the value the next step waits on) BEFORE xout.
//   (3) chain shape = R2 (2 sub-acc depth 4; R5 proved depth irrelevant).
// Everything else (xout staging, chunk-boundary coalesced stores, two-barrier
// publish, xb in epilogue) unchanged.
// ---------------------------------------------------------------------------
__global__ __launch_bounds__(512, 2) void rnn_scan(
    const float* __restrict__ h0, const float* __restrict__ W_h,
    float* __restrict__ out) {
  __shared__ __align__(16) unsigned short hb0[DH];
  __shared__ __align__(16) unsigned short hb1[DH];
  __shared__ __align__(16) float xpb[2][16 * DH];
  __shared__ __align__(16) float xout[16 * DH];

  const int tid  = threadIdx.x;
  const int lane = tid & 63;
  const int w    = tid >> 6;         // 0..7
  const int l15  = lane & 15;
  const int lg   = lane >> 4;
  const int koff = lg * 8;
  const int b    = blockIdx.x;
  float* outb = out + (size_t)b * T_LEN * DH;

  // Issue chunk-0 x_proj loads first so they fly under the W_h fragment load.
  f32x4 st[2];
#pragma unroll
  for (int i = 0; i < 2; ++i)
    st[i] = *(const f32x4*)(outb + i * 2048 + tid * 4);

  // W_h bf16 fragments: wave w owns cols [32w, 32w+32) as 2 16-col tiles.
  short8 Bf[2][8];
#pragma unroll
  for (int n = 0; n < 2; ++n) {
    const int c = 32 * w + 16 * n + l15;
#pragma unroll
    for (int kk = 0; kk < 8; ++kk) {
      short8 bf;
#pragma unroll
      for (int j = 0; j < 8; ++j)
        bf[j] = (short)f2bf(W_h[(32 * kk + koff + j) * DH + c]);
      Bf[n][kk] = bf;
    }
  }

  if (tid < DH) hb0[tid] = f2bf(h0[b * DH + tid]);
#pragma unroll
  for (int i = 0; i < 2; ++i)
    *(f32x4*)(&xpb[0][i * 2048 + tid * 4]) = st[i];
#pragma unroll
  for (int i = 0; i < 2; ++i)
    st[i] = *(const f32x4*)(outb + 4096 + i * 2048 + tid * 4);
  __syncthreads();

  // A fragments: rows 1..15 are zeros, set ONCE; only l15==0 lanes overwrite.
  short8 A[8];
#pragma unroll
  for (int kk = 0; kk < 8; ++kk) A[kk] = (short8){0, 0, 0, 0, 0, 0, 0, 0};

  // One scan step: read h from hbR, write h_{t+1} to hbW.
  auto STEP = [&](const unsigned short* hbR, unsigned short* hbW, int t) {
    if (l15 == 0) {
#pragma unroll
      for (int kk = 0; kk < 8; ++kk)
        A[kk] = *(const short8*)(hbR + 32 * kk + koff);
    }
    // x_proj(+biases), read early (consumed at the very end).
    float xb[2];
    if (lane < 16) {
#pragma unroll
      for (int n = 0; n < 2; ++n)
        xb[n] = xpb[(t >> 4) & 1][(t & 15) * DH + 32 * w + 16 * n + lane];
    }

    // 16 MFMAs: 2 col-tiles x 2 sub-accumulators of depth 4.
    f32x4 ac[2][2];
#pragma unroll
    for (int n = 0; n < 2; ++n) {
      ac[n][0] = (f32x4){0.f, 0.f, 0.f, 0.f};
      ac[n][1] = (f32x4){0.f, 0.f, 0.f, 0.f};
    }
#pragma unroll
    for (int kk = 0; kk < 4; ++kk)
#pragma unroll
      for (int n = 0; n < 2; ++n)
        ac[n][0] = __builtin_amdgcn_mfma_f32_16x16x32_bf16(A[kk], Bf[n][kk], ac[n][0], 0, 0, 0);
#pragma unroll
    for (int kk = 4; kk < 8; ++kk)
#pragma unroll
      for (int n = 0; n < 2; ++n)
        ac[n][1] = __builtin_amdgcn_mfma_f32_16x16x32_bf16(A[kk], Bf[n][kk], ac[n][1], 0, 0, 0);

    // Valid output row is m=0 -> lanes 0..15, element 0.
    // hbW write FIRST (next step's critical dependency), xout second.
    if (lane < 16) {
      float v[2];
#pragma unroll
      for (int n = 0; n < 2; ++n) {
        v[n] = (ac[n][0][0] + ac[n][1][0]) + xb[n];
        v[n] = fmaxf(v[n], 0.0f);
        hbW[32 * w + 16 * n + lane] = f2bf(v[n]);
      }
#pragma unroll
      for (int n = 0; n < 2; ++n)
        xout[(t & 15) * DH + 32 * w + 16 * n + lane] = v[n];
    }
  };

  for (int i = 0; i < T_LEN / 2; ++i) {
    const int t0 = 2 * i;
    STEP(hb0, hb1, t0);
    WG_BARRIER();
    STEP(hb1, hb0, t0 + 1);

    if ((i & 7) == 7) {
      WG_BARRIER();  // all reads of xp chunk + h/xout writes complete
      const int cc = t0 >> 4;     // finished chunk
      const int nc = cc + 1;
      if (nc < NCHUNK) {
        // publish prefetched chunk (waits vmcnt(2): 2 stores newer than loads)
#pragma unroll
        for (int k = 0; k < 2; ++k)
          *(f32x4*)(&xpb[nc & 1][k * 2048 + tid * 4]) = st[k];
        const int pc = nc + 1;
        if (pc < NCHUNK) {
#pragma unroll
          for (int k = 0; k < 2; ++k)
            st[k] = *(const f32x4*)(outb + (size_t)pc * 4096 + k * 2048 + tid * 4);
        }
      }
      // dump finished h chunk: LDS -> regs -> coalesced global stores
      f32x4 o[2];
#pragma unroll
      for (int k = 0; k < 2; ++k)
        o[k] = *(const f32x4*)(&xout[k * 2048 + tid * 4]);
#pragma unroll
      for (int k = 0; k < 2; ++k)
        *(f32x4*)(outb + (size_t)cc * 4096 + k * 2048 + tid * 4) = o[k];
      WG_BARRIER();  // xpb chunk + xout reuse visible before next step
    } else {
      WG_BARRIER();  // h_{t+1} visible before next step's A-frag reads
    }
  }
}

extern "C" void kernel_launch(void* const* d_in, const int* in_sizes, int n_in,
                              void* d_out, int out_size, void* d_ws, size_t ws_size,
                              hipStream_t stream) {
  const float* x    = (const float*)d_in[0];
  const float* h0   = (const float*)d_in[1];
  const float* W_in = (const float*)d_in[2];
  const float* b_in = (const float*)d_in[3];
  const float* W_h  = (const float*)d_in[4];
  const float* b_h  = (const float*)d_in[5];
  float* out = (float*)d_out;

  hipLaunchKernelGGL(xproj_gemm, dim3(512), dim3(256), 0, stream, x, W_in, b_in, b_h, out);
  hipLaunchKernelGGL(rnn_scan, dim3(32), dim3(512), 0, stream, h0, W_h, out);
}